// Round 7
// baseline (40.054 us; speedup 1.0000x reference)
//
#include <hip/hip_runtime.h>

#define E 128
#define Fb 32
#define TSH 136    // u16 stride per LDS table row (272 B)
#define ROWB 272   // table row byte stride

__device__ inline float bf2f(unsigned short u) {
    union { unsigned int i; float f; } x;
    x.i = ((unsigned int)u) << 16;
    return x.f;
}

// ---------------- Kernel 1: table (blocks 0..63) + ranks (blocks 64..319) ---
// table: T[a,c] = sum_u rcp(|u-a|)*rcp(|u-c|) - S(a)S(c)/127, bf16 RNE.
// ranks: stable rank = #{j: x_j<x_e} + #{j<e: x_j==x_e}  (argsort(argsort))
//        computed with float4 LDS broadcasts (4 candidates per DS op) +
//        VALU compares -> off the DS-pipe bottleneck.
__global__ __launch_bounds__(256) void spearman_prep(
        const float* __restrict__ de,
        unsigned char* __restrict__ ranks,
        unsigned char* __restrict__ ranksT2,
        unsigned short* __restrict__ table) {
    const int tid = threadIdx.x;

    if (blockIdx.x < 64) {
        // ---- table blocks: 256 entries each (2 rows of T) ----
        __shared__ float rcp[E];
        if (tid < E) rcp[tid] = 1.0f / (float)(tid + 1);
        __syncthreads();
        int idx = (int)blockIdx.x * 256 + tid;
        int a = idx >> 7, c = idx & 127;
        float sa = 0.f, sc = 0.f, g = 0.f;
#pragma unroll 16
        for (int u = 0; u < E; ++u) {
            float wa = rcp[abs(u - a)];
            float wc = rcp[abs(u - c)];
            sa += wa;
            sc += wc;
            g += wa * wc;
        }
        float t = g - sa * sc * (1.0f / (float)(E - 1));
        union { float f; unsigned int i; } x;
        x.f = t;
        unsigned int r = (x.i + 0x7FFFu + ((x.i >> 16) & 1u)) >> 16;  // RNE bf16
        table[idx] = (unsigned short)r;
        return;
    }

    // ---- rank blocks: one (batch b, freq-half fh) slab of 128e x 16f ----
    __shared__ __align__(16) float xs[16][132];          // 8.4 KB, rows 16B-aligned
    __shared__ __align__(16) unsigned char rt[16][128];  // 2 KB
    const int bid = (int)blockIdx.x - 64;
    const int b = bid >> 1, fh = bid & 1;

    {
        const int e = tid & 127, q = tid >> 7;   // q in {0,1}
#pragma unroll
        for (int p = 0; p < 2; ++p) {
            const int f4 = q * 2 + p;            // float4 group 0..3 within 16 f
            float4 v = *(const float4*)(de + ((size_t)(b * E + e)) * Fb + fh * 16 + f4 * 4);
            xs[f4 * 4 + 0][e] = v.x;
            xs[f4 * 4 + 1][e] = v.y;
            xs[f4 * 4 + 2][e] = v.z;
            xs[f4 * 4 + 3][e] = v.w;
        }
    }
    __syncthreads();

    // all-pairs count: wave wv owns f in [wv*4, wv*4+4); lane holds e=lane
    // and e=lane+64. j-sweep via uniform float4 broadcast reads.
    const int wv = tid >> 6, lane = tid & 63;
#pragma unroll
    for (int fi = 0; fi < 4; ++fi) {
        const int f = wv * 4 + fi;
        const float v0 = xs[f][lane];
        const float v1 = xs[f][lane + 64];
        int c0 = 0, c1 = 0;
        const float4* row = (const float4*)&xs[f][0];
#pragma unroll 8
        for (int j4 = 0; j4 < E / 4; ++j4) {
            float4 q4 = row[j4];
            int j = j4 * 4;
            c0 += (int)(q4.x < v0) + (int)((q4.x == v0) & (j + 0 < lane));
            c0 += (int)(q4.y < v0) + (int)((q4.y == v0) & (j + 1 < lane));
            c0 += (int)(q4.z < v0) + (int)((q4.z == v0) & (j + 2 < lane));
            c0 += (int)(q4.w < v0) + (int)((q4.w == v0) & (j + 3 < lane));
            c1 += (int)(q4.x < v1) + (int)((q4.x == v1) & (j + 0 < lane + 64));
            c1 += (int)(q4.y < v1) + (int)((q4.y == v1) & (j + 1 < lane + 64));
            c1 += (int)(q4.z < v1) + (int)((q4.z == v1) & (j + 2 < lane + 64));
            c1 += (int)(q4.w < v1) + (int)((q4.w == v1) & (j + 3 < lane + 64));
        }
        rt[f][lane] = (unsigned char)c0;
        rt[f][lane + 64] = (unsigned char)c1;
    }
    __syncthreads();

    // coalesced dumps of both layouts (ranksT2 holds rank*2 = byte offsets)
    if (tid < 128) {
        const int f = tid >> 3, e0 = (tid & 7) * 16;
        *(uint4*)(ranks + ((size_t)b * Fb + fh * 16 + f) * E + e0) = *(const uint4*)&rt[f][e0];
        const int e = tid;
        unsigned int w[4];
#pragma unroll
        for (int g = 0; g < 4; ++g) {
            w[g] = ((unsigned)rt[g * 4 + 0][e] * 2)
                 | (((unsigned)rt[g * 4 + 1][e] * 2) << 8)
                 | (((unsigned)rt[g * 4 + 2][e] * 2) << 16)
                 | (((unsigned)rt[g * 4 + 3][e] * 2) << 24);
        }
        *(uint4*)(ranksT2 + ((size_t)b * E + e) * Fb + fh * 16) =
            make_uint4(w[0], w[1], w[2], w[3]);
    }
}

// ---------------- Kernel 2: out[b,j,k] = mean_f T[rj, rk], symmetric -------
// (round-4 body: 6 tiles of 32x64 per batch + transpose mirrors; ranksT2
//  already prescaled to byte offsets)
__global__ __launch_bounds__(256, 3) void spearman_acc(
        const unsigned char* __restrict__ ranks,
        const unsigned char* __restrict__ ranksT2,
        const unsigned short* __restrict__ table,
        float* __restrict__ out) {
    __shared__ __align__(16) unsigned short tbl[E * TSH];  // 34816 B
    __shared__ __align__(16) float trans[64 * 33];         // 8448 B
    const int tid = threadIdx.x;
    const int b = blockIdx.x / 6;
    const int t = blockIdx.x % 6;
    const int ti  = (t < 4) ? (t >> 1) : (t - 2);   // {0,0,1,1,2,3}
    const int cb  = (t < 4) ? (t & 1) : 1;          // {0,1,0,1,1,1}
    const int mir = (t < 4) ? (t & 1) : 0;          // {0,1,0,1,0,0}
    const int j0 = ti * 32, k0 = cb * 64;

    const int wave = tid >> 6, lane = tid & 63;
    const int k = k0 + lane;
    const unsigned char* rb  = ranks   + b * (Fb * E);
    const unsigned char* rbT = ranksT2 + b * (Fb * E);

    int rk2[Fb];
#pragma unroll
    for (int f4 = 0; f4 < 8; ++f4) {
        uchar4 qv = *(const uchar4*)&rbT[k * Fb + f4 * 4];
        rk2[f4 * 4 + 0] = (int)qv.x;
        rk2[f4 * 4 + 1] = (int)qv.y;
        rk2[f4 * 4 + 2] = (int)qv.z;
        rk2[f4 * 4 + 3] = (int)qv.w;
    }

    int rj272[4];
#pragma unroll
    for (int rp = 0; rp < 4; ++rp) {
        int fl = rp * 8 + (lane >> 3);
        int row = j0 + wave + 4 * (lane & 7);
        rj272[rp] = (int)rb[fl * E + row] * ROWB;
    }

    const uint4* t16 = (const uint4*)table;
#pragma unroll
    for (int i = 0; i < 8; ++i) {
        int idx = tid + i * 256;
        uint4 v = t16[idx];
        int a = idx >> 4;
        int c = (idx & 15) * 8;
        *(uint4*)&tbl[a * TSH + c] = v;
    }
    __syncthreads();

    float acc[8] = {0.f, 0.f, 0.f, 0.f, 0.f, 0.f, 0.f, 0.f};
#pragma unroll
    for (int f = 0; f < Fb; ++f) {
        const int rg = f >> 3, li = (f & 7) << 3;
        const int ck = rk2[f];
#pragma unroll
        for (int g = 0; g < 8; ++g) {
            int ro = __builtin_amdgcn_readlane(rj272[rg], li | g);
            acc[g] += bf2f(*(const unsigned short*)((const char*)tbl + ro + ck));
        }
    }

    const float s = 1.0f / (float)Fb;
    float* ob = out + b * (E * E);
#pragma unroll
    for (int g = 0; g < 8; ++g)
        ob[(j0 + wave + 4 * g) * E + k] = acc[g] * s;

    if (mir) {
#pragma unroll
        for (int g = 0; g < 8; ++g)
            trans[lane * 33 + (wave + 4 * g)] = acc[g] * s;
        __syncthreads();
#pragma unroll
        for (int g = 0; g < 8; ++g) {
            int rr = (tid >> 5) + 8 * g;
            int cc = tid & 31;
            ob[(k0 + rr) * E + (j0 + cc)] = trans[rr * 33 + cc];
        }
    }
}

extern "C" void kernel_launch(void* const* d_in, const int* in_sizes, int n_in,
                              void* d_out, int out_size, void* d_ws, size_t ws_size,
                              hipStream_t stream) {
    const float* de = (const float*)d_in[0];     // [128,128,32] f32
    float* out = (float*)d_out;                  // [128,128,128] f32

    const int B = 128;
    unsigned char* ranks   = (unsigned char*)d_ws;                         // 512KB
    unsigned char* ranksT2 = (unsigned char*)d_ws + (size_t)B * Fb * E;    // 512KB
    unsigned short* table  = (unsigned short*)((char*)d_ws + 2 * (size_t)B * Fb * E);  // 32KB

    spearman_prep<<<64 + B * 2, 256, 0, stream>>>(de, ranks, ranksT2, table);
    spearman_acc<<<B * 6, 256, 0, stream>>>(ranks, ranksT2, table, out);
}

// Round 8
// 27.871 us; speedup vs baseline: 1.4371x; 1.4371x over previous
//
#include <hip/hip_runtime.h>

#define E 128
#define Fb 32
#define TSH 136    // u16 stride per LDS table row (272 B)
#define ROWB 272   // table row byte stride

__device__ inline float bf2f(unsigned short u) {
    union { unsigned int i; float f; } x;
    x.i = ((unsigned int)u) << 16;
    return x.f;
}

// monotone bijection f32 -> u32 (ascending), finite values
__device__ inline unsigned int sortable(float f) {
    union { float f; unsigned int u; } x;
    x.f = f;
    unsigned int u = x.u;
    return (u & 0x80000000u) ? ~u : (u | 0x80000000u);
}

// ---------------- Kernel 1: table (blocks 0..63) + ranks (blocks 64..319) ---
// table: T[a,c] = sum_u rcp(|u-a|)*rcp(|u-c|) - S(a)S(c)/127, bf16 RNE.
// ranks: stable rank = #{j: key_j < key_e}, key = (sortable(x)<<7)|e.
// Candidate sweep done via v_readlane register broadcasts (literal lane
// indices) + v_cmp_lt_u64 on the VALU -- zero DS traffic in the scan.
__global__ __launch_bounds__(256) void spearman_prep(
        const float* __restrict__ de,
        unsigned char* __restrict__ ranks,
        unsigned char* __restrict__ ranksT2,
        unsigned short* __restrict__ table) {
    const int tid = threadIdx.x;

    if (blockIdx.x < 64) {
        // ---- table blocks: 256 entries each (2 rows of T) ----
        __shared__ float rcp[E];
        if (tid < E) rcp[tid] = 1.0f / (float)(tid + 1);
        __syncthreads();
        int idx = (int)blockIdx.x * 256 + tid;
        int a = idx >> 7, c = idx & 127;
        float sa = 0.f, sc = 0.f, g = 0.f;
#pragma unroll 16
        for (int u = 0; u < E; ++u) {
            float wa = rcp[abs(u - a)];
            float wc = rcp[abs(u - c)];
            sa += wa;
            sc += wc;
            g += wa * wc;
        }
        float t = g - sa * sc * (1.0f / (float)(E - 1));
        union { float f; unsigned int i; } x;
        x.f = t;
        unsigned int r = (x.i + 0x7FFFu + ((x.i >> 16) & 1u)) >> 16;  // RNE bf16
        table[idx] = (unsigned short)r;
        return;
    }

    // ---- rank blocks: one (batch b, freq-half fh) slab of 128e x 16f ----
    // wave wv owns global freqs fbase..fbase+3; lane holds e=lane and e=lane+64.
    __shared__ __align__(16) unsigned char rt[16][128];  // 2 KB
    const int bid = (int)blockIdx.x - 64;
    const int b = bid >> 1, fh = bid & 1;
    const int wv = tid >> 6, lane = tid & 63;
    const int fbase = fh * 16 + wv * 4;

    const float4 vA = *(const float4*)(de + ((size_t)(b * E + lane)) * Fb + fbase);
    const float4 vB = *(const float4*)(de + ((size_t)(b * E + lane + 64)) * Fb + fbase);

    unsigned long long kA[4], kB[4];
    kA[0] = ((unsigned long long)sortable(vA.x) << 7) | (unsigned)lane;
    kA[1] = ((unsigned long long)sortable(vA.y) << 7) | (unsigned)lane;
    kA[2] = ((unsigned long long)sortable(vA.z) << 7) | (unsigned)lane;
    kA[3] = ((unsigned long long)sortable(vA.w) << 7) | (unsigned)lane;
    kB[0] = ((unsigned long long)sortable(vB.x) << 7) | (unsigned)(lane + 64);
    kB[1] = ((unsigned long long)sortable(vB.y) << 7) | (unsigned)(lane + 64);
    kB[2] = ((unsigned long long)sortable(vB.z) << 7) | (unsigned)(lane + 64);
    kB[3] = ((unsigned long long)sortable(vB.w) << 7) | (unsigned)(lane + 64);

    int c0[4] = {0, 0, 0, 0}, c1[4] = {0, 0, 0, 0};
#pragma unroll
    for (int j = 0; j < 64; ++j) {
#pragma unroll
        for (int fi = 0; fi < 4; ++fi) {
            unsigned int lo = (unsigned int)__builtin_amdgcn_readlane((int)(unsigned int)kA[fi], j);
            unsigned int hi = (unsigned int)__builtin_amdgcn_readlane((int)(unsigned int)(kA[fi] >> 32), j);
            unsigned long long cand = ((unsigned long long)hi << 32) | lo;
            c0[fi] += (int)(cand < kA[fi]);
            c1[fi] += (int)(cand < kB[fi]);
        }
    }
#pragma unroll
    for (int j = 0; j < 64; ++j) {
#pragma unroll
        for (int fi = 0; fi < 4; ++fi) {
            unsigned int lo = (unsigned int)__builtin_amdgcn_readlane((int)(unsigned int)kB[fi], j);
            unsigned int hi = (unsigned int)__builtin_amdgcn_readlane((int)(unsigned int)(kB[fi] >> 32), j);
            unsigned long long cand = ((unsigned long long)hi << 32) | lo;
            c0[fi] += (int)(cand < kA[fi]);
            c1[fi] += (int)(cand < kB[fi]);
        }
    }

#pragma unroll
    for (int fi = 0; fi < 4; ++fi) {
        rt[wv * 4 + fi][lane] = (unsigned char)c0[fi];
        rt[wv * 4 + fi][lane + 64] = (unsigned char)c1[fi];
    }
    __syncthreads();

    // coalesced dumps of both layouts (ranksT2 holds rank*2 = byte offsets)
    if (tid < 128) {
        const int f = tid >> 3, e0 = (tid & 7) * 16;
        *(uint4*)(ranks + ((size_t)b * Fb + fh * 16 + f) * E + e0) = *(const uint4*)&rt[f][e0];
        const int e = tid;
        unsigned int w[4];
#pragma unroll
        for (int g = 0; g < 4; ++g) {
            w[g] = ((unsigned)rt[g * 4 + 0][e] * 2)
                 | (((unsigned)rt[g * 4 + 1][e] * 2) << 8)
                 | (((unsigned)rt[g * 4 + 2][e] * 2) << 16)
                 | (((unsigned)rt[g * 4 + 3][e] * 2) << 24);
        }
        *(uint4*)(ranksT2 + ((size_t)b * E + e) * Fb + fh * 16) =
            make_uint4(w[0], w[1], w[2], w[3]);
    }
}

// ---------------- Kernel 2: out[b,j,k] = mean_f T[rj, rk], symmetric -------
// (round-4 body: 6 tiles of 32x64 per batch + transpose mirrors; ranksT2
//  already prescaled to byte offsets)
__global__ __launch_bounds__(256, 3) void spearman_acc(
        const unsigned char* __restrict__ ranks,
        const unsigned char* __restrict__ ranksT2,
        const unsigned short* __restrict__ table,
        float* __restrict__ out) {
    __shared__ __align__(16) unsigned short tbl[E * TSH];  // 34816 B
    __shared__ __align__(16) float trans[64 * 33];         // 8448 B
    const int tid = threadIdx.x;
    const int b = blockIdx.x / 6;
    const int t = blockIdx.x % 6;
    const int ti  = (t < 4) ? (t >> 1) : (t - 2);   // {0,0,1,1,2,3}
    const int cb  = (t < 4) ? (t & 1) : 1;          // {0,1,0,1,1,1}
    const int mir = (t < 4) ? (t & 1) : 0;          // {0,1,0,1,0,0}
    const int j0 = ti * 32, k0 = cb * 64;

    const int wave = tid >> 6, lane = tid & 63;
    const int k = k0 + lane;
    const unsigned char* rb  = ranks   + b * (Fb * E);
    const unsigned char* rbT = ranksT2 + b * (Fb * E);

    int rk2[Fb];
#pragma unroll
    for (int f4 = 0; f4 < 8; ++f4) {
        uchar4 qv = *(const uchar4*)&rbT[k * Fb + f4 * 4];
        rk2[f4 * 4 + 0] = (int)qv.x;
        rk2[f4 * 4 + 1] = (int)qv.y;
        rk2[f4 * 4 + 2] = (int)qv.z;
        rk2[f4 * 4 + 3] = (int)qv.w;
    }

    int rj272[4];
#pragma unroll
    for (int rp = 0; rp < 4; ++rp) {
        int fl = rp * 8 + (lane >> 3);
        int row = j0 + wave + 4 * (lane & 7);
        rj272[rp] = (int)rb[fl * E + row] * ROWB;
    }

    const uint4* t16 = (const uint4*)table;
#pragma unroll
    for (int i = 0; i < 8; ++i) {
        int idx = tid + i * 256;
        uint4 v = t16[idx];
        int a = idx >> 4;
        int c = (idx & 15) * 8;
        *(uint4*)&tbl[a * TSH + c] = v;
    }
    __syncthreads();

    float acc[8] = {0.f, 0.f, 0.f, 0.f, 0.f, 0.f, 0.f, 0.f};
#pragma unroll
    for (int f = 0; f < Fb; ++f) {
        const int rg = f >> 3, li = (f & 7) << 3;
        const int ck = rk2[f];
#pragma unroll
        for (int g = 0; g < 8; ++g) {
            int ro = __builtin_amdgcn_readlane(rj272[rg], li | g);
            acc[g] += bf2f(*(const unsigned short*)((const char*)tbl + ro + ck));
        }
    }

    const float s = 1.0f / (float)Fb;
    float* ob = out + b * (E * E);
#pragma unroll
    for (int g = 0; g < 8; ++g)
        ob[(j0 + wave + 4 * g) * E + k] = acc[g] * s;

    if (mir) {
#pragma unroll
        for (int g = 0; g < 8; ++g)
            trans[lane * 33 + (wave + 4 * g)] = acc[g] * s;
        __syncthreads();
#pragma unroll
        for (int g = 0; g < 8; ++g) {
            int rr = (tid >> 5) + 8 * g;
            int cc = tid & 31;
            ob[(k0 + rr) * E + (j0 + cc)] = trans[rr * 33 + cc];
        }
    }
}

extern "C" void kernel_launch(void* const* d_in, const int* in_sizes, int n_in,
                              void* d_out, int out_size, void* d_ws, size_t ws_size,
                              hipStream_t stream) {
    const float* de = (const float*)d_in[0];     // [128,128,32] f32
    float* out = (float*)d_out;                  // [128,128,128] f32

    const int B = 128;
    unsigned char* ranks   = (unsigned char*)d_ws;                         // 512KB
    unsigned char* ranksT2 = (unsigned char*)d_ws + (size_t)B * Fb * E;    // 512KB
    unsigned short* table  = (unsigned short*)((char*)d_ws + 2 * (size_t)B * Fb * E);  // 32KB

    spearman_prep<<<64 + B * 2, 256, 0, stream>>>(de, ranks, ranksT2, table);
    spearman_acc<<<B * 6, 256, 0, stream>>>(ranks, ranksT2, table, out);
}